// Round 1
// baseline (501.436 us; speedup 1.0000x reference)
//
#include <hip/hip_runtime.h>
#include <float.h>
#include <math.h>

// Problem constants
#define D_REAL 2331   // 259 channels * 3*3 patch
#define D_PAD  2336   // bf16 matrix row length
#define DQ     2304   // fp8 matrix row length (resp dims only; 18*128)
#define N_REAL 7225   // 85*85 patches
#define N_PAD  7424   // 29*256
#define NT     29     // 256-wide output tiles per dim

typedef __attribute__((ext_vector_type(8))) short bf16x8_t;  // 8 bf16 = 4 VGPRs
typedef __attribute__((ext_vector_type(4))) float f32x4_t;   // 16x16 MFMA C/D
typedef __attribute__((ext_vector_type(8))) int   v8i_t;     // MX A/B operand
typedef __attribute__((ext_vector_type(4))) int   v4i_t;

__device__ __forceinline__ unsigned short f2bf(float x) {
    union { float f; unsigned int u; } v; v.f = x;
    unsigned int r = v.u + 0x7FFFu + ((v.u >> 16) & 1u);   // RNE
    return (unsigned short)(r >> 16);
}
__device__ __forceinline__ float bflo(unsigned int u) {
    union { unsigned int x; float f; } v; v.x = u << 16; return v.f;
}
__device__ __forceinline__ float bfhi(unsigned int u) {
    union { unsigned int x; float f; } v; v.x = u & 0xFFFF0000u; return v.f;
}

#define GLOAD_LDS16(g, l) __builtin_amdgcn_global_load_lds( \
    (const __attribute__((address_space(1))) void*)(g),     \
    (__attribute__((address_space(3))) void*)(l), 16, 0, 0)

// ---------------------------------------------------------------------------
// Fused build: resp part -> bf16 Pb[n][0..2304) AND fp8 Pq[n][0..2304);
// map part -> bf16 Pb[n][2304..2336) only (50 * avgpool4 + zero pad).
__global__ __launch_bounds__(256) void build_all(
        const float* __restrict__ respS, const float* __restrict__ respI,
        const float* __restrict__ mapS,  const float* __restrict__ mapI,
        unsigned short* __restrict__ PbS, unsigned short* __restrict__ PbI,
        unsigned char* __restrict__ PqS, unsigned char* __restrict__ PqI) {
    const int mat = blockIdx.y;
    unsigned short* Pb = mat ? PbI : PbS;
    const int bx = blockIdx.x;
    if (bx < 6120) {
        const float* resp = mat ? respI : respS;
        unsigned char* Pq = mat ? PqI : PqS;
        __shared__ float slab[5 * 768];        // [cc][rr][col], 15 KB max
        const int u  = bx / 72;                // 0..84
        const int d0 = (bx - u * 72) * 32;     // 0..2272
        const int c0 = d0 / 9;
        const int cN = (d0 + 31) / 9 - c0 + 1; // <= 5
        const int total = cN * 768;
        for (int idx = threadIdx.x; idx < total; idx += 256) {
            int cc = idx / 768;
            int rem = idx - cc * 768;          // (row-3u)*256 + col
            slab[idx] = resp[(((size_t)(c0 + cc)) << 16) + ((size_t)(3 * u) << 8) + rem];
        }
        __syncthreads();
        const int dl16 = threadIdx.x & 15;     // d-pair index
        const int de = d0 + 2 * dl16, dq = de + 1;
        const int ce = de / 9, re = de - ce * 9, pe = re / 3, qe = re - pe * 3;
        const int co = dq / 9, ro = dq - co * 9, po = ro / 3, qo = ro - po * 3;
        const int base_e = (ce - c0) * 768 + pe * 256 + qe;
        const int base_o = (co - c0) * 768 + po * 256 + qo;
        const int v0 = threadIdx.x >> 4;       // 0..15
        for (int v = v0; v < 85; v += 16) {
            float x0 = slab[base_e + 3 * v];
            float x1 = slab[base_o + 3 * v];
            size_t row = (size_t)(u * 85 + v);
            *(unsigned int*)&Pb[row * D_PAD + de] =
                (unsigned int)f2bf(x0) | ((unsigned int)f2bf(x1) << 16);
            int pk = __builtin_amdgcn_cvt_pk_fp8_f32(x0, x1, 0, false);
            *(unsigned short*)&Pq[row * DQ + de] = (unsigned short)pk;
        }
    } else {
        const float* map = mat ? mapI : mapS;
        int t = (bx - 6120) * 256 + threadIdx.x;
        int n = t >> 5, dm = t & 31;
        if (n >= N_REAL) return;
        float val = 0.f;
        if (dm < 27) {
            int u = n / 85, v = n - u * 85;
            int ch = dm / 9, r9 = dm - ch * 9, p = r9 / 3, q = r9 - p * 3;
            const float* mp = map + ((size_t)ch << 20)
                                  + ((size_t)((3 * u + p) * 4) << 10)
                                  + (size_t)((3 * v + q) * 4);
            float s = 0.f;
            #pragma unroll
            for (int a = 0; a < 4; a++)
                #pragma unroll
                for (int b = 0; b < 4; b++) s += mp[a * 1024 + b];
            val = 3.125f * s;                  // 50 * (1/16)
        }
        Pb[(size_t)n * D_PAD + 2304 + dm] = f2bf(val);
    }
}

// ---------------------------------------------------------------------------
// sinv[n] = 1/||S[:,n]|| (bf16 matrix); also zeroes the loss accumulator.
__global__ __launch_bounds__(256) void col_norms(const unsigned short* __restrict__ Sb,
                                                 float* __restrict__ sinv,
                                                 double* __restrict__ accum) {
    if (blockIdx.x == 0 && threadIdx.x == 0) *accum = 0.0;
    int n = blockIdx.x * 4 + (threadIdx.x >> 6);
    int lane = threadIdx.x & 63;
    const uint4* sp = (const uint4*)(Sb + (size_t)n * D_PAD);
    float s = 0.f;
    for (int k = lane; k < D_PAD / 8; k += 64) {
        uint4 a = sp[k];
        float x0 = bflo(a.x), x1 = bfhi(a.x), x2 = bflo(a.y), x3 = bfhi(a.y);
        float x4 = bflo(a.z), x5 = bfhi(a.z), x6 = bflo(a.w), x7 = bfhi(a.w);
        s = fmaf(x0, x0, s); s = fmaf(x1, x1, s);
        s = fmaf(x2, x2, s); s = fmaf(x3, x3, s);
        s = fmaf(x4, x4, s); s = fmaf(x5, x5, s);
        s = fmaf(x6, x6, s); s = fmaf(x7, x7, s);
    }
    #pragma unroll
    for (int off = 32; off > 0; off >>= 1) s += __shfl_xor(s, off);
    if (lane == 0) sinv[n] = (n < N_REAL) ? rsqrtf(s) : 0.f;
}

// ---------------------------------------------------------------------------
// 256x256-tile MX-fp8 GEMM + fused argmax, 8-wave (2x4), 8-phase counted-vmcnt
// schedule (T3+T4+T5 from the technique catalog). K: 18 x (16x16x128 f8f6f4,
// unit scales) + 1 x (16x16x32 bf16) over the 50x-weighted map dims.
// LDS 128 KiB: Af/Bf[2][256][128] fp8 double-buffer. Staging is octant-wise
// (8 KB = 2 global_load_lds x 512 thr / phase-pair): octant s of tile T+2 is
// issued exactly one phase after tile T's compute frees it; landing is gated
// by s_waitcnt vmcnt(6) ONLY at local phases 3/7 (never 0 in the main loop),
// raw s_barrier (no compiler drain), s_setprio(1) around each 8-MFMA cluster.
// XOR chunk swizzle (chunk ^= row&7) folded into the global source address.
__global__ __launch_bounds__(512, 2) void gemm_argmax(
        const unsigned char* __restrict__ Sq, const unsigned char* __restrict__ Iq,
        const unsigned short* __restrict__ Sb, const unsigned short* __restrict__ Ib,
        const float* __restrict__ sinv,
        float* __restrict__ pval, int* __restrict__ pidx) {
    const int bid = blockIdx.x;
    const int it = bid % NT, jt = bid / NT;    // consecutive bids share B panel
    const int i0 = it * 256, j0 = jt * 256;

    __shared__ __align__(16) unsigned char Af[2][256][128];   // 64 KB
    __shared__ __align__(16) unsigned char Bf[2][256][128];   // 64 KB

    const int tid = threadIdx.x;
    const int L = tid & 63, w = tid >> 6;      // 8 waves
    const int wr = w >> 2, wc = w & 3;         // 2x4 wave grid -> 128x64/wave
    const int m = L & 15, q = L >> 4;
    const int clo = ((2 * q)     ^ (m & 7)) << 4;   // swizzled 16B chunk offs
    const int chi = ((2 * q + 1) ^ (m & 7)) << 4;

    f32x4_t acc[8][4];
    #pragma unroll
    for (int a = 0; a < 8; a++)
        #pragma unroll
        for (int b = 0; b < 4; b++) acc[a][b] = (f32x4_t){0.f, 0.f, 0.f, 0.f};

    // Octant staging (wave-uniform LDS dest, swizzle pre-applied on source).
    // A-octant s: rows {32s..32s+31} u {128+32s..128+32s+31}; B-octant s:
    // rows {64s..64s+63}. Per octant: 512 thr x 16 B, wave w -> 8 rows.
    const int aro = 128 * (w >> 2) + 8 * (w & 3);
    const int bro = 8 * w;
    const unsigned char* pA = Sq + (size_t)(i0 + aro + (L >> 3)) * DQ
                            + (((L & 7) ^ (L >> 3)) << 4);
    const unsigned char* pB = Iq + (size_t)(j0 + bro + (L >> 3)) * DQ
                            + (((L & 7) ^ (L >> 3)) << 4);

#define STG_A(s, ko, b) GLOAD_LDS16(pA + (size_t)(32 * (s)) * DQ + (ko), \
                                    &Af[b][32 * (s) + aro][0])
#define STG_B(s, ko, b) GLOAD_LDS16(pB + (size_t)(64 * (s)) * DQ + (ko), \
                                    &Bf[b][64 * (s) + bro][0])

#define LDA8(dst, b, mi) {                                              \
    const unsigned char* p_ = &Af[b][wr * 128 + (mi) * 16 + m][0];      \
    v4i_t lo_ = *(const v4i_t*)(p_ + clo);                              \
    v4i_t hi_ = *(const v4i_t*)(p_ + chi);                              \
    dst = __builtin_shufflevector(lo_, hi_, 0, 1, 2, 3, 4, 5, 6, 7); }
#define LDB8(dst, b, nj) {                                              \
    const unsigned char* p_ = &Bf[b][wc * 64 + (nj) * 16 + m][0];       \
    v4i_t lo_ = *(const v4i_t*)(p_ + clo);                              \
    v4i_t hi_ = *(const v4i_t*)(p_ + chi);                              \
    dst = __builtin_shufflevector(lo_, hi_, 0, 1, 2, 3, 4, 5, 6, 7); }

#define RDB4(b) LDB8(bq0, b, 0) LDB8(bq1, b, 1) LDB8(bq2, b, 2) LDB8(bq3, b, 3)

#define MXMFMA(a, b, c) __builtin_amdgcn_mfma_scale_f32_16x16x128_f8f6f4( \
    a, b, c, 0, 0, 0, 0x7F, 0, 0x7F)

// One phase: {ds_read subtile || issue octant stages} -> barrier ->
// lgkmcnt(0) -> setprio(1) MFMA x8 setprio(0) -> [vmcnt gate] -> barrier.
#define PHASE(b, p2, RDB, STAGES, TAILW) {                              \
    v8i_t a0_, a1_;                                                     \
    RDB                                                                 \
    LDA8(a0_, b, 2 * (p2))                                              \
    LDA8(a1_, b, 2 * (p2) + 1)                                          \
    STAGES                                                              \
    __builtin_amdgcn_sched_barrier(0);                                  \
    __builtin_amdgcn_s_barrier();                                       \
    asm volatile("s_waitcnt lgkmcnt(0)" ::: "memory");                  \
    __builtin_amdgcn_sched_barrier(0);                                  \
    __builtin_amdgcn_s_setprio(1);                                      \
    acc[2*(p2)  ][0] = MXMFMA(a0_, bq0, acc[2*(p2)  ][0]);              \
    acc[2*(p2)  ][1] = MXMFMA(a0_, bq1, acc[2*(p2)  ][1]);              \
    acc[2*(p2)  ][2] = MXMFMA(a0_, bq2, acc[2*(p2)  ][2]);              \
    acc[2*(p2)  ][3] = MXMFMA(a0_, bq3, acc[2*(p2)  ][3]);              \
    acc[2*(p2)+1][0] = MXMFMA(a1_, bq0, acc[2*(p2)+1][0]);              \
    acc[2*(p2)+1][1] = MXMFMA(a1_, bq1, acc[2*(p2)+1][1]);              \
    acc[2*(p2)+1][2] = MXMFMA(a1_, bq2, acc[2*(p2)+1][2]);              \
    acc[2*(p2)+1][3] = MXMFMA(a1_, bq3, acc[2*(p2)+1][3]);              \
    __builtin_amdgcn_s_setprio(0);                                      \
    __builtin_amdgcn_sched_barrier(0);                                  \
    TAILW                                                               \
    __builtin_amdgcn_s_barrier();                                       \
}

    v8i_t bq0, bq1, bq2, bq3;

    // Prologue: tile 0 (all 8 octants, buf0) + tile 1 (6 octants, buf1).
    STG_B(0, 0, 0); STG_A(0, 0, 0);
    STG_B(1, 0, 0); STG_A(1, 0, 0);
    STG_B(2, 0, 0); STG_A(2, 0, 0);
    STG_B(3, 0, 0); STG_A(3, 0, 0);
    STG_B(0, 128, 1); STG_A(0, 128, 1);
    STG_B(1, 128, 1); STG_A(1, 128, 1);
    STG_B(2, 128, 1); STG_A(2, 128, 1);
    asm volatile("s_waitcnt vmcnt(6)" ::: "memory");   // tile 0 landed
    __builtin_amdgcn_s_barrier();

    // Main loop: iter i computes tiles 2i (buf0, phases 0-3) and 2i+1 (buf1,
    // phases 4-7); stages tile 2i+1 s3 (P0), tile 2i+2 (P1-P4), tile 2i+3
    // s0-2 (P5-P7). ko offsets are relative to pA/pB at K byte 256*i.
    #pragma unroll 1
    for (int i8 = 0; i8 < 8; ++i8) {
        PHASE(0, 0, RDB4(0), STG_B(3, 128, 1); STG_A(3, 128, 1);, )
        PHASE(0, 1, ,        STG_B(0, 256, 0); STG_A(0, 256, 0);, )
        PHASE(0, 2, ,        STG_B(1, 256, 0); STG_A(1, 256, 0);, )
        PHASE(0, 3, ,        STG_B(2, 256, 0); STG_A(2, 256, 0);,
              asm volatile("s_waitcnt vmcnt(6)" ::: "memory");)
        PHASE(1, 0, RDB4(1), STG_B(3, 256, 0); STG_A(3, 256, 0);, )
        PHASE(1, 1, ,        STG_B(0, 384, 1); STG_A(0, 384, 1);, )
        PHASE(1, 2, ,        STG_B(1, 384, 1); STG_A(1, 384, 1);, )
        PHASE(1, 3, ,        STG_B(2, 384, 1); STG_A(2, 384, 1);,
              asm volatile("s_waitcnt vmcnt(6)" ::: "memory");)
        pA += 256; pB += 256;
    }

    // Final iteration: tiles 16 (buf0) / 17 (buf1); bf16 map-dim tail staged
    // into the freed buf0 overlays during phases 4-7.
    unsigned short (*At)[32] = (unsigned short(*)[32])&Af[0][0][0];
    unsigned short (*Bt)[32] = (unsigned short(*)[32])&Bf[0][0][0];
    const unsigned short* ptA = Sb + (size_t)(i0 + 16 * w + (L >> 2)) * D_PAD
                              + 2304 + (((L & 3) ^ ((L >> 3) & 3)) << 3);
    const unsigned short* ptB = Ib + (size_t)(j0 + 16 * w + (L >> 2)) * D_PAD
                              + 2304 + (((L & 3) ^ ((L >> 3) & 3)) << 3);

    PHASE(0, 0, RDB4(0), STG_B(3, 128, 1); STG_A(3, 128, 1);, )
    PHASE(0, 1, , , )
    PHASE(0, 2, , , )
    PHASE(0, 3, , , asm volatile("s_waitcnt vmcnt(0)" ::: "memory");)
    PHASE(1, 0, RDB4(1), GLOAD_LDS16(ptA, &At[16 * w][0]);, )
    PHASE(1, 1, , GLOAD_LDS16(ptA + (size_t)128 * D_PAD, &At[128 + 16 * w][0]);, )
    PHASE(1, 2, , GLOAD_LDS16(ptB, &Bt[16 * w][0]);, )
    PHASE(1, 3, , GLOAD_LDS16(ptB + (size_t)128 * D_PAD, &Bt[128 + 16 * w][0]);,
          asm volatile("s_waitcnt vmcnt(0)" ::: "memory");)
#undef PHASE
#undef RDB4
#undef STG_A
#undef STG_B

    {   // bf16 tail (K=32 over the 50x map dims), same f32 accumulators
        const int cht = (q ^ ((m >> 1) & 3)) << 3;
        bf16x8_t bt[4];
        #pragma unroll
        for (int nj = 0; nj < 4; nj++)
            bt[nj] = *(const bf16x8_t*)&Bt[wc * 64 + nj * 16 + m][cht];
        #pragma unroll
        for (int mi = 0; mi < 8; mi++) {
            bf16x8_t a_ = *(const bf16x8_t*)&At[wr * 128 + mi * 16 + m][cht];
            #pragma unroll
            for (int nj = 0; nj < 4; nj++)
                acc[mi][nj] = __builtin_amdgcn_mfma_f32_16x16x32_bf16(
                    a_, bt[nj], acc[mi][nj], 0, 0, 0);
        }
    }

    // Epilogue. C/D layout: col = m (j-dir), row = q*4 + reg (i-dir).
    float sjv[4];
    #pragma unroll
    for (int nj = 0; nj < 4; nj++) sjv[nj] = sinv[j0 + wc * 64 + nj * 16 + m];
    #pragma unroll
    for (int mi = 0; mi < 8; mi++) {
        #pragma unroll
        for (int r = 0; r < 4; r++) {
            float best = -INFINITY; int bidx = 0x7fffffff;
            #pragma unroll
            for (int nj = 0; nj < 4; nj++) {   // j ascending -> '>' keeps smallest
                int j = j0 + wc * 64 + nj * 16 + m;
                float v = (j < N_REAL) ? acc[mi][nj][r] * sjv[nj] : -INFINITY;
                if (v > best) { best = v; bidx = j; }
            }
            #pragma unroll
            for (int off = 1; off < 16; off <<= 1) {
                float ov = __shfl_xor(best, off);
                int   oi = __shfl_xor(bidx, off);
                if (ov > best || (ov == best && oi < bidx)) { best = ov; bidx = oi; }
            }
            if (m == 0) {
                int i = i0 + wr * 128 + mi * 16 + q * 4 + r;
                pval[(size_t)jt * N_PAD + i] = best;
                pidx[(size_t)jt * N_PAD + i] = bidx;
            }
        }
    }
}

// ---------------------------------------------------------------------------
// Fused merge + loss (reads bf16 matrices -> precision as before).
__global__ __launch_bounds__(256) void loss_kernel(
        const unsigned short* __restrict__ Ib, const unsigned short* __restrict__ Sb,
        const float* __restrict__ pval, const int* __restrict__ pidx,
        double* __restrict__ accum) {
    __shared__ float wsum[4];
    __shared__ int sjn;
    const int n = blockIdx.x;
    if (threadIdx.x < 64) {                    // wave 0: merge 29 partials
        float v = -INFINITY; int id = 0x7fffffff;
        if (threadIdx.x < NT) {
            v  = pval[(size_t)threadIdx.x * N_PAD + n];
            id = pidx[(size_t)threadIdx.x * N_PAD + n];
        }
        #pragma unroll
        for (int off = 32; off > 0; off >>= 1) {
            float ov = __shfl_xor(v, off);
            int   oi = __shfl_xor(id, off);
            if (ov > v || (ov == v && oi < id)) { v = ov; id = oi; }
        }
        if (threadIdx.x == 0) sjn = id;
    }
    __syncthreads();
    const int jn = sjn;
    const uint4* ip = (const uint4*)(Ib + (size_t)n  * D_PAD);
    const uint4* sp = (const uint4*)(Sb + (size_t)jn * D_PAD);
    float s = 0.f;
    for (int k = threadIdx.x; k < D_PAD / 8; k += 256) {
        uint4 a = ip[k], b = sp[k];
        float d0 = bflo(a.x) - bflo(b.x), d1 = bfhi(a.x) - bfhi(b.x);
        float d2 = bflo(a.y) - bflo(b.y), d3 = bfhi(a.y) - bfhi(b.y);
        float d4 = bflo(a.z) - bflo(b.z), d5 = bfhi(a.z) - bfhi(b.z);
        float d6 = bflo(a.w) - bflo(b.w), d7 = bfhi(a.w) - bfhi(b.w);
        s = fmaf(d0, d0, s); s = fmaf(d1, d1, s);
        s = fmaf(d2, d2, s); s = fmaf(d3, d3, s);
        s = fmaf(d4, d4, s); s = fmaf(d5, d5, s);
        s = fmaf(d6, d6, s); s = fmaf(d7, d7, s);
    }
    #pragma unroll
    for (int off = 32; off > 0; off >>= 1) s += __shfl_xor(s, off);
    int lane = threadIdx.x & 63, wv = threadIdx.x >> 6;
    if (lane == 0) wsum[wv] = s;
    __syncthreads();
    if (threadIdx.x == 0) {
        double t = (double)wsum[0] + (double)wsum[1] + (double)wsum[2] + (double)wsum[3];
        atomicAdd(accum, t);
    }
}

__global__ void finalize(const double* __restrict__ accum, float* __restrict__ out) {
    out[0] = (float)(accum[0] / (double)((long long)D_REAL * N_REAL));
}

// ---------------------------------------------------------------------------
extern "C" void kernel_launch(void* const* d_in, const int* in_sizes, int n_in,
                              void* d_out, int out_size, void* d_ws, size_t ws_size,
                              hipStream_t stream) {
    const float* style_resp = (const float*)d_in[0];
    const float* style_map  = (const float*)d_in[1];
    const float* output_map = (const float*)d_in[2];
    const float* model_resp = (const float*)d_in[3];
    float* out = (float*)d_out;

    unsigned short* Sb = (unsigned short*)d_ws;
    unsigned short* Ib = Sb + (size_t)D_PAD * N_PAD;
    unsigned char*  Sq = (unsigned char*)(Ib + (size_t)D_PAD * N_PAD);
    unsigned char*  Iq = Sq + (size_t)DQ * N_PAD;
    float* sinv    = (float*)(Iq + (size_t)DQ * N_PAD);
    float* pval    = sinv + N_PAD;
    int*   pidx    = (int*)(pval + (size_t)NT * N_PAD);
    double* accum  = (double*)(pidx + (size_t)NT * N_PAD);

    // resp tiles: 85*72 = 6120 blocks; map part: ceil(7225*32/256) = 904 blocks
    build_all<<<dim3(6120 + 904, 2), 256, 0, stream>>>(
        style_resp, model_resp, style_map, output_map, Sb, Ib, Sq, Iq);

    col_norms<<<N_PAD / 4, 256, 0, stream>>>(Sb, sinv, accum);

    gemm_argmax<<<NT * NT, 512, 0, stream>>>(Sq, Iq, Sb, Ib, sinv, pval, pidx);

    loss_kernel<<<N_REAL, 256, 0, stream>>>(Ib, Sb, pval, pidx, accum);
    finalize<<<1, 1, 0, stream>>>(accum, out);
}

// Round 2
// 498.129 us; speedup vs baseline: 1.0066x; 1.0066x over previous
//
#include <hip/hip_runtime.h>
#include <float.h>
#include <math.h>

// Problem constants
#define D_REAL 2331   // 259 channels * 3*3 patch
#define D_PAD  2336   // bf16 matrix row length
#define DQ     2304   // fp8 matrix row length (resp dims only; 18*128)
#define N_REAL 7225   // 85*85 patches
#define N_PAD  7296   // 57*128
#define JTILES 57     // 128-wide j tiles
#define ITILES 57

typedef __attribute__((ext_vector_type(8))) short bf16x8_t;  // 8 bf16 = 4 VGPRs
typedef __attribute__((ext_vector_type(4))) float f32x4_t;   // 16x16 MFMA C/D
typedef __attribute__((ext_vector_type(8))) int   v8i_t;     // MX A/B operand
typedef __attribute__((ext_vector_type(4))) int   v4i_t;

__device__ __forceinline__ unsigned short f2bf(float x) {
    union { float f; unsigned int u; } v; v.f = x;
    unsigned int r = v.u + 0x7FFFu + ((v.u >> 16) & 1u);   // RNE
    return (unsigned short)(r >> 16);
}
__device__ __forceinline__ float bflo(unsigned int u) {
    union { unsigned int x; float f; } v; v.x = u << 16; return v.f;
}
__device__ __forceinline__ float bfhi(unsigned int u) {
    union { unsigned int x; float f; } v; v.x = u & 0xFFFF0000u; return v.f;
}

#define GLOAD_LDS16(g, l) __builtin_amdgcn_global_load_lds( \
    (const __attribute__((address_space(1))) void*)(g),     \
    (__attribute__((address_space(3))) void*)(l), 16, 0, 0)

// ---------------------------------------------------------------------------
// Fused build: resp part -> bf16 Pb[n][0..2304) AND fp8 Pq[n][0..2304);
// map part -> bf16 Pb[n][2304..2336) only (50 * avgpool4 + zero pad).
__global__ __launch_bounds__(256) void build_all(
        const float* __restrict__ respS, const float* __restrict__ respI,
        const float* __restrict__ mapS,  const float* __restrict__ mapI,
        unsigned short* __restrict__ PbS, unsigned short* __restrict__ PbI,
        unsigned char* __restrict__ PqS, unsigned char* __restrict__ PqI) {
    const int mat = blockIdx.y;
    unsigned short* Pb = mat ? PbI : PbS;
    const int bx = blockIdx.x;
    if (bx < 6120) {
        const float* resp = mat ? respI : respS;
        unsigned char* Pq = mat ? PqI : PqS;
        __shared__ float slab[5 * 768];        // [cc][rr][col], 15 KB max
        const int u  = bx / 72;                // 0..84
        const int d0 = (bx - u * 72) * 32;     // 0..2272
        const int c0 = d0 / 9;
        const int cN = (d0 + 31) / 9 - c0 + 1; // <= 5
        const int total = cN * 768;
        for (int idx = threadIdx.x; idx < total; idx += 256) {
            int cc = idx / 768;
            int rem = idx - cc * 768;          // (row-3u)*256 + col
            slab[idx] = resp[(((size_t)(c0 + cc)) << 16) + ((size_t)(3 * u) << 8) + rem];
        }
        __syncthreads();
        const int dl16 = threadIdx.x & 15;     // d-pair index
        const int de = d0 + 2 * dl16, dq = de + 1;
        const int ce = de / 9, re = de - ce * 9, pe = re / 3, qe = re - pe * 3;
        const int co = dq / 9, ro = dq - co * 9, po = ro / 3, qo = ro - po * 3;
        const int base_e = (ce - c0) * 768 + pe * 256 + qe;
        const int base_o = (co - c0) * 768 + po * 256 + qo;
        const int v0 = threadIdx.x >> 4;       // 0..15
        for (int v = v0; v < 85; v += 16) {
            float x0 = slab[base_e + 3 * v];
            float x1 = slab[base_o + 3 * v];
            size_t row = (size_t)(u * 85 + v);
            *(unsigned int*)&Pb[row * D_PAD + de] =
                (unsigned int)f2bf(x0) | ((unsigned int)f2bf(x1) << 16);
            int pk = __builtin_amdgcn_cvt_pk_fp8_f32(x0, x1, 0, false);
            *(unsigned short*)&Pq[row * DQ + de] = (unsigned short)pk;
        }
    } else {
        const float* map = mat ? mapI : mapS;
        int t = (bx - 6120) * 256 + threadIdx.x;
        int n = t >> 5, dm = t & 31;
        if (n >= N_REAL) return;
        float val = 0.f;
        if (dm < 27) {
            int u = n / 85, v = n - u * 85;
            int ch = dm / 9, r9 = dm - ch * 9, p = r9 / 3, q = r9 - p * 3;
            const float* mp = map + ((size_t)ch << 20)
                                  + ((size_t)((3 * u + p) * 4) << 10)
                                  + (size_t)((3 * v + q) * 4);
            float s = 0.f;
            #pragma unroll
            for (int a = 0; a < 4; a++)
                #pragma unroll
                for (int b = 0; b < 4; b++) s += mp[a * 1024 + b];
            val = 3.125f * s;                  // 50 * (1/16)
        }
        Pb[(size_t)n * D_PAD + 2304 + dm] = f2bf(val);
    }
}

// ---------------------------------------------------------------------------
// sinv[n] = 1/||S[:,n]|| (bf16 matrix); also zeroes the loss accumulator.
__global__ __launch_bounds__(256) void col_norms(const unsigned short* __restrict__ Sb,
                                                 float* __restrict__ sinv,
                                                 double* __restrict__ accum) {
    if (blockIdx.x == 0 && threadIdx.x == 0) *accum = 0.0;
    int n = blockIdx.x * 4 + (threadIdx.x >> 6);
    int lane = threadIdx.x & 63;
    const uint4* sp = (const uint4*)(Sb + (size_t)n * D_PAD);
    float s = 0.f;
    for (int k = lane; k < D_PAD / 8; k += 64) {
        uint4 a = sp[k];
        float x0 = bflo(a.x), x1 = bfhi(a.x), x2 = bflo(a.y), x3 = bfhi(a.y);
        float x4 = bflo(a.z), x5 = bfhi(a.z), x6 = bflo(a.w), x7 = bfhi(a.w);
        s = fmaf(x0, x0, s); s = fmaf(x1, x1, s);
        s = fmaf(x2, x2, s); s = fmaf(x3, x3, s);
        s = fmaf(x4, x4, s); s = fmaf(x5, x5, s);
        s = fmaf(x6, x6, s); s = fmaf(x7, x7, s);
    }
    #pragma unroll
    for (int off = 32; off > 0; off >>= 1) s += __shfl_xor(s, off);
    if (lane == 0) sinv[n] = (n < N_REAL) ? rsqrtf(s) : 0.f;
}

// ---------------------------------------------------------------------------
// 128x128-tile MX-fp8 GEMM + fused argmax. Occupancy-first redesign:
// 64 KiB LDS + <=128 unified regs -> 2 blocks/CU, 16 waves/CU (4/SIMD),
// two INDEPENDENT blocks per CU let barrier phases slip against each other
// (R0 vs R1 showed both schedules stuck at 25% MfmaUtil with 2 waves/SIMD).
// Schedule: 2 phases per 128B K-tile, counted vmcnt(3) gate once per tile
// (never 0 in steady state), raw s_barrier, setprio around MFMA cluster,
// XOR chunk swizzle pre-applied to the global source address.
// A is stored with a bit5<->bit6 row permute so each staging half (64 LDS
// rows, one global_load_lds) exactly matches one phase's read set:
//   P0 reads global A rows {0-31,64-95}   = LDS rows 0-63   (stage half 0)
//   P1 reads global A rows {32-63,96-127} = LDS rows 64-127 (stage half 1)
// B is fully consumed in P0 (both nj frags), so both B halves stage in P1.
__global__ __launch_bounds__(512, 4) void gemm_argmax(
        const unsigned char* __restrict__ Sq, const unsigned char* __restrict__ Iq,
        const unsigned short* __restrict__ Sb, const unsigned short* __restrict__ Ib,
        const float* __restrict__ sinv,
        float* __restrict__ pval, int* __restrict__ pidx) {
    const int bid = blockIdx.x;
    const int it = bid % ITILES, jt = bid / ITILES;  // consecutive bids share B panel
    const int i0 = it * 128, j0 = jt * 128;

    __shared__ __align__(16) unsigned char Af[2][128][128];   // 32 KB
    __shared__ __align__(16) unsigned char Bf[2][128][128];   // 32 KB

    const int tid = threadIdx.x;
    const int L = tid & 63, w = tid >> 6;      // 8 waves
    const int wr = w >> 2, wc = w & 3;         // 2x4 wave grid -> 64x32/wave
    const int m = L & 15, q = L >> 4;
    const int clo = ((2 * q)     ^ (m & 7)) << 4;   // swizzled 16B chunk offs
    const int chi = ((2 * q + 1) ^ (m & 7)) << 4;

    f32x4_t acc[4][2];
    #pragma unroll
    for (int a = 0; a < 4; a++)
        #pragma unroll
        for (int b = 0; b < 2; b++) acc[a][b] = (f32x4_t){0.f, 0.f, 0.f, 0.f};

    // Staging: one global_load_lds instr = 512 thr x 16B = 8 KB = 64 LDS rows.
    // Wave w covers LDS rows 8w..8w+7 (linear dest). Chunk swizzle
    // stored[row][pos] = global[row][pos ^ (row&7)] via the source address.
    const int r8 = 8 * w + (L >> 3);                    // 0..63
    const int swz = ((L & 7) ^ (L >> 3)) << 4;
    // A row permute: LDS row (64h + r) holds global row r + (r&32) + 32h.
    const unsigned char* pA = Sq + (size_t)(i0 + r8 + (r8 & 32)) * DQ + swz;
    const unsigned char* pB = Iq + (size_t)(j0 + r8) * DQ + swz;

#define STG_A(h, ko, b) GLOAD_LDS16(pA + (size_t)(32 * (h)) * DQ + (ko), \
                                    &Af[b][64 * (h) + 8 * w][0])
#define STG_B(h, ko, b) GLOAD_LDS16(pB + (size_t)(64 * (h)) * DQ + (ko), \
                                    &Bf[b][64 * (h) + 8 * w][0])

    // Read side: global A row wr*64+mi*16+m sits at LDS row with bits 5,6
    // swapped -> (mi>>1)*64 + wr*32 + (mi&1)*16 + m (compile-time mi).
#define LDA8(dst, b, mi) {                                                    \
    const unsigned char* p_ =                                                 \
        &Af[b][(((mi) >> 1) << 6) + (wr << 5) + (((mi) & 1) << 4) + m][0];    \
    v4i_t lo_ = *(const v4i_t*)(p_ + clo);                                    \
    v4i_t hi_ = *(const v4i_t*)(p_ + chi);                                    \
    dst = __builtin_shufflevector(lo_, hi_, 0, 1, 2, 3, 4, 5, 6, 7); }
#define LDB8(dst, b, nj) {                                                    \
    const unsigned char* p_ = &Bf[b][(wc << 5) + ((nj) << 4) + m][0];         \
    v4i_t lo_ = *(const v4i_t*)(p_ + clo);                                    \
    v4i_t hi_ = *(const v4i_t*)(p_ + chi);                                    \
    dst = __builtin_shufflevector(lo_, hi_, 0, 1, 2, 3, 4, 5, 6, 7); }

#define RDB2(b) LDB8(bq0, b, 0) LDB8(bq1, b, 1)

#define MXMFMA(a, b, c) __builtin_amdgcn_mfma_scale_f32_16x16x128_f8f6f4( \
    a, b, c, 0, 0, 0, 0x7F, 0, 0x7F)

#define GATE3 asm volatile("s_waitcnt vmcnt(3)" ::: "memory");
#define GATE0 asm volatile("s_waitcnt vmcnt(0)" ::: "memory");

// One phase: {ds_read frags || issue stages} -> barrier -> lgkmcnt(0) ->
// setprio(1) MFMA x4 setprio(0) -> [vmcnt gate] -> barrier.
#define PHASE(b, h, RDB, STAGES, GATE) {                                \
    v8i_t a0_, a1_;                                                     \
    RDB                                                                 \
    LDA8(a0_, b, 2 * (h))                                               \
    LDA8(a1_, b, 2 * (h) + 1)                                           \
    STAGES                                                              \
    __builtin_amdgcn_sched_barrier(0);                                  \
    __builtin_amdgcn_s_barrier();                                       \
    asm volatile("s_waitcnt lgkmcnt(0)" ::: "memory");                  \
    __builtin_amdgcn_sched_barrier(0);                                  \
    __builtin_amdgcn_s_setprio(1);                                      \
    acc[2*(h)  ][0] = MXMFMA(a0_, bq0, acc[2*(h)  ][0]);                \
    acc[2*(h)  ][1] = MXMFMA(a0_, bq1, acc[2*(h)  ][1]);                \
    acc[2*(h)+1][0] = MXMFMA(a1_, bq0, acc[2*(h)+1][0]);                \
    acc[2*(h)+1][1] = MXMFMA(a1_, bq1, acc[2*(h)+1][1]);                \
    __builtin_amdgcn_s_setprio(0);                                      \
    __builtin_amdgcn_sched_barrier(0);                                  \
    GATE                                                                \
    __builtin_amdgcn_s_barrier();                                       \
}

    v8i_t bq0, bq1;

    // Prologue: tile0 full (4 instr) + tile1 B-halves + A-half0 (3 instr).
    // Gate vmcnt(3): tile0 landed, tile1's 3 in flight.
    STG_B(0, 0, 0); STG_B(1, 0, 0); STG_A(0, 0, 0); STG_A(1, 0, 0);
    STG_B(0, 128, 1); STG_B(1, 128, 1); STG_A(0, 128, 1);
    GATE3
    __builtin_amdgcn_s_barrier();

    // Main loop: iter p computes tiles u=2p (buf0) and u+1 (buf1).
    // u.P0 stages A(u+1)h1; u.P1 stages B(u+2)+A(u+2)h0, gate vmcnt(3)
    // (drains exactly tile u+1's 4); u+1.P0 stages A(u+2)h1; u+1.P1
    // stages B(u+3)+A(u+3)h0, gate vmcnt(3) (drains tile u+2's 4).
    #pragma unroll 1
    for (int p = 0; p < 8; ++p) {
        PHASE(0, 0, RDB2(0), STG_A(1, 128, 1);, )
        PHASE(0, 1, ,        STG_B(0, 256, 0); STG_B(1, 256, 0); STG_A(0, 256, 0);, GATE3)
        PHASE(1, 0, RDB2(1), STG_A(1, 256, 0);, )
        PHASE(1, 1, ,        STG_B(0, 384, 1); STG_B(1, 384, 1); STG_A(0, 384, 1);, GATE3)
        pA += 256; pB += 256;
    }

    // Tiles 16 (buf0) / 17 (buf1) + bf16 map-dim tail into the freed buf0.
    unsigned short (*At)[32] = (unsigned short(*)[32])&Af[0][0][0];
    unsigned short (*Bt)[32] = (unsigned short(*)[32])&Bf[0][0][0];
    const unsigned short* ptA = Sb + (size_t)(i0 + 16 * w + (L >> 2)) * D_PAD
                              + 2304 + (((L & 3) ^ ((L >> 3) & 3)) << 3);
    const unsigned short* ptB = Ib + (size_t)(j0 + 16 * w + (L >> 2)) * D_PAD
                              + 2304 + (((L & 3) ^ ((L >> 3) & 3)) << 3);

    PHASE(0, 0, RDB2(0), STG_A(1, 128, 1);, )         // t16.P0: A(17)h1
    PHASE(0, 1, , , GATE0)                            // t16.P1: tile17 landed
    PHASE(1, 0, RDB2(1),
          GLOAD_LDS16(ptA, &At[16 * w][0]);
          GLOAD_LDS16(ptB, &Bt[16 * w][0]);, )        // t17.P0: stage tail
    PHASE(1, 1, , , GATE0)                            // t17.P1: tail landed
#undef PHASE
#undef RDB2
#undef STG_A
#undef STG_B

    {   // bf16 tail (K=32 over the 50x map dims), same f32 accumulators
        const int cht = (q ^ ((m >> 1) & 3)) << 3;
        bf16x8_t bt0 = *(const bf16x8_t*)&Bt[(wc << 5) + m][cht];
        bf16x8_t bt1 = *(const bf16x8_t*)&Bt[(wc << 5) + 16 + m][cht];
        #pragma unroll
        for (int mi = 0; mi < 4; mi++) {
            bf16x8_t a_ = *(const bf16x8_t*)&At[(wr << 6) + mi * 16 + m][cht];
            acc[mi][0] = __builtin_amdgcn_mfma_f32_16x16x32_bf16(
                a_, bt0, acc[mi][0], 0, 0, 0);
            acc[mi][1] = __builtin_amdgcn_mfma_f32_16x16x32_bf16(
                a_, bt1, acc[mi][1], 0, 0, 0);
        }
    }

    // Epilogue. C/D layout: col = m (j-dir), row = q*4 + reg (i-dir).
    const float sj0 = sinv[j0 + (wc << 5) + m];
    const float sj1 = sinv[j0 + (wc << 5) + 16 + m];
    #pragma unroll
    for (int mi = 0; mi < 4; mi++) {
        #pragma unroll
        for (int r = 0; r < 4; r++) {
            float best = -INFINITY; int bidx = 0x7fffffff;
            {
                int j = j0 + (wc << 5) + m;            // nj=0 then nj=1: ascending
                float v = (j < N_REAL) ? acc[mi][0][r] * sj0 : -INFINITY;
                if (v > best) { best = v; bidx = j; }
                j += 16;
                v = (j < N_REAL) ? acc[mi][1][r] * sj1 : -INFINITY;
                if (v > best) { best = v; bidx = j; }
            }
            #pragma unroll
            for (int off = 1; off < 16; off <<= 1) {   // reduce 16 m-lanes
                float ov = __shfl_xor(best, off);
                int   oi = __shfl_xor(bidx, off);
                if (ov > best || (ov == best && oi < bidx)) { best = ov; bidx = oi; }
            }
            if (m == 0) {
                int i = i0 + (wr << 6) + mi * 16 + (q << 2) + r;
                pval[(size_t)jt * N_PAD + i] = best;
                pidx[(size_t)jt * N_PAD + i] = bidx;
            }
        }
    }
}

// ---------------------------------------------------------------------------
// Fused merge + loss (reads bf16 matrices -> precision as before).
__global__ __launch_bounds__(256) void loss_kernel(
        const unsigned short* __restrict__ Ib, const unsigned short* __restrict__ Sb,
        const float* __restrict__ pval, const int* __restrict__ pidx,
        double* __restrict__ accum) {
    __shared__ float wsum[4];
    __shared__ int sjn;
    const int n = blockIdx.x;
    if (threadIdx.x < 64) {                    // wave 0: merge 57 partials
        float v = -INFINITY; int id = 0x7fffffff;
        if (threadIdx.x < JTILES) {
            v  = pval[(size_t)threadIdx.x * N_PAD + n];
            id = pidx[(size_t)threadIdx.x * N_PAD + n];
        }
        #pragma unroll
        for (int off = 32; off > 0; off >>= 1) {
            float ov = __shfl_xor(v, off);
            int   oi = __shfl_xor(id, off);
            if (ov > v || (ov == v && oi < id)) { v = ov; id = oi; }
        }
        if (threadIdx.x == 0) sjn = id;
    }
    __syncthreads();
    const int jn = sjn;
    const uint4* ip = (const uint4*)(Ib + (size_t)n  * D_PAD);
    const uint4* sp = (const uint4*)(Sb + (size_t)jn * D_PAD);
    float s = 0.f;
    for (int k = threadIdx.x; k < D_PAD / 8; k += 256) {
        uint4 a = ip[k], b = sp[k];
        float d0 = bflo(a.x) - bflo(b.x), d1 = bfhi(a.x) - bfhi(b.x);
        float d2 = bflo(a.y) - bflo(b.y), d3 = bfhi(a.y) - bfhi(b.y);
        float d4 = bflo(a.z) - bflo(b.z), d5 = bfhi(a.z) - bfhi(b.z);
        float d6 = bflo(a.w) - bflo(b.w), d7 = bfhi(a.w) - bfhi(b.w);
        s = fmaf(d0, d0, s); s = fmaf(d1, d1, s);
        s = fmaf(d2, d2, s); s = fmaf(d3, d3, s);
        s = fmaf(d4, d4, s); s = fmaf(d5, d5, s);
        s = fmaf(d6, d6, s); s = fmaf(d7, d7, s);
    }
    #pragma unroll
    for (int off = 32; off > 0; off >>= 1) s += __shfl_xor(s, off);
    int lane = threadIdx.x & 63, wv = threadIdx.x >> 6;
    if (lane == 0) wsum[wv] = s;
    __syncthreads();
    if (threadIdx.x == 0) {
        double t = (double)wsum[0] + (double)wsum[1] + (double)wsum[2] + (double)wsum[3];
        atomicAdd(accum, t);
    }
}

__global__ void finalize(const double* __restrict__ accum, float* __restrict__ out) {
    out[0] = (float)(accum[0] / (double)((long long)D_REAL * N_REAL));
}

// ---------------------------------------------------------------------------
extern "C" void kernel_launch(void* const* d_in, const int* in_sizes, int n_in,
                              void* d_out, int out_size, void* d_ws, size_t ws_size,
                              hipStream_t stream) {
    const float* style_resp = (const float*)d_in[0];
    const float* style_map  = (const float*)d_in[1];
    const float* output_map = (const float*)d_in[2];
    const float* model_resp = (const float*)d_in[3];
    float* out = (float*)d_out;

    unsigned short* Sb = (unsigned short*)d_ws;
    unsigned short* Ib = Sb + (size_t)D_PAD * N_PAD;
    unsigned char*  Sq = (unsigned char*)(Ib + (size_t)D_PAD * N_PAD);
    unsigned char*  Iq = Sq + (size_t)DQ * N_PAD;
    float* sinv    = (float*)(Iq + (size_t)DQ * N_PAD);
    float* pval    = sinv + N_PAD;
    int*   pidx    = (int*)(pval + (size_t)JTILES * N_PAD);
    double* accum  = (double*)(pidx + (size_t)JTILES * N_PAD);

    // resp tiles: 85*72 = 6120 blocks; map part: ceil(7225*32/256) = 904 blocks
    build_all<<<dim3(6120 + 904, 2), 256, 0, stream>>>(
        style_resp, model_resp, style_map, output_map, Sb, Ib, Sq, Iq);

    col_norms<<<N_PAD / 4, 256, 0, stream>>>(Sb, sinv, accum);

    gemm_argmax<<<ITILES * JTILES, 512, 0, stream>>>(Sq, Iq, Sb, Ib, sinv, pval, pidx);

    loss_kernel<<<N_REAL, 256, 0, stream>>>(Ib, Sb, pval, pidx, accum);
    finalize<<<1, 1, 0, stream>>>(accum, out);
}